// Round 1
// baseline (669.347 us; speedup 1.0000x reference)
//
#include <hip/hip_runtime.h>

// MPS memory encoder: B=2048 chains, 128 sites, FEAT=64, BOND=32, OUT=256.
// res'[b,r] = sum_d res[b,d] * m[b,d,r],  m[b,d,r] = sum_f x[b,n,f]*core[n,d,f,r]
// Strategy: per site, per 16-batch tile, compute m^T[c=(d*32+r), b] via
// mfma_f32_16x16x32_bf16 with A = transposed bf16 cores (f contiguous),
// B = x tile (LDS). Stage-2 (batch-diagonal res@m) on VALU + LDS reduce.

#define NSITES 128
#define FEATD  64
#define BOND   32
#define OUTD   256
#define BTILE  16
#define NWAVES 8          // 512 threads
#define CTW    8          // c-tiles per wave (64 tiles of 16 c-rows / 8 waves)

typedef __attribute__((ext_vector_type(8))) short short8;
typedef __attribute__((ext_vector_type(4))) float float4v;

__device__ __forceinline__ ushort f2bf(float f) {
    union { float f; unsigned u; } v; v.f = f;
    unsigned r = v.u + 0x7FFFu + ((v.u >> 16) & 1u);   // RNE, finite inputs
    return (ushort)(r >> 16);
}

// cores [n][d][f][r] fp32  ->  core_t [n][c=d*32+r][f] bf16
__global__ void prep_cores(const float* __restrict__ cores,
                           ushort* __restrict__ core_t) {
    int nd = blockIdx.x;              // n*32 + d, 4096 blocks
    int t  = threadIdx.x;             // 256
    int r  = t >> 3;
    int f0 = (t & 7) * 8;
    const float* src = cores + (size_t)nd * (FEATD * BOND) + r;  // + f*BOND
    ushort tmp[8];
#pragma unroll
    for (int j = 0; j < 8; ++j) tmp[j] = f2bf(src[(size_t)(f0 + j) * BOND]);
    uint4 w;
    w.x = (unsigned)tmp[0] | ((unsigned)tmp[1] << 16);
    w.y = (unsigned)tmp[2] | ((unsigned)tmp[3] << 16);
    w.z = (unsigned)tmp[4] | ((unsigned)tmp[5] << 16);
    w.w = (unsigned)tmp[6] | ((unsigned)tmp[7] << 16);
    *(uint4*)(core_t + ((size_t)nd * BOND + r) * FEATD + f0) = w;
}

template <bool USE_T>
__global__ __launch_bounds__(512)
void mps_chain(const float* __restrict__ x, const float* __restrict__ cores,
               const ushort* __restrict__ core_t,
               const float* __restrict__ startv, const float* __restrict__ endv,
               const float* __restrict__ fc_w, const float* __restrict__ fc_b,
               float* __restrict__ out) {
    // LDS layouts chosen for bank behavior:
    //  x_lds stride 72 (144B rows, 16B aligned for ds_read_b128)
    //  res_lds stride 36; part[w][r][b] stride 18 -> <=2-way conflicts (free)
    __shared__ __align__(16) ushort x_lds[BTILE][72];
    __shared__ float res_lds[BTILE][36];
    __shared__ float part[NWAVES][BOND][18];
    __shared__ float val_lds[BTILE];

    const int t    = threadIdx.x;
    const int wave = t >> 6;
    const int lane = t & 63;
    const int b16  = lane & 15;       // batch within tile / MFMA 16-dim
    const int q    = lane >> 4;       // quad -> k-group of 8
    const int b0   = blockIdx.x * BTILE;

    // init res[b][d] = start[d]
    {
        int b = t >> 5, d = t & 31;   // 512 threads = 16*32 exactly
        res_lds[b][d] = startv[d];
    }
    // load + stage x for site 0 (2 floats per thread)
    {
        int e = t * 2, b = e >> 6, f = e & 63;
        float2 x0 = *(const float2*)(x + ((size_t)(b0 + b) * NSITES + 0) * FEATD + f);
        x_lds[b][f]     = f2bf(x0.x);
        x_lds[b][f + 1] = f2bf(x0.y);
    }
    __syncthreads();

    for (int n = 0; n < NSITES; ++n) {
        // prefetch x for site n+1 into registers (hide HBM latency)
        float2 xnext;
        if (n + 1 < NSITES) {
            int e = t * 2, b = e >> 6, f = e & 63;
            xnext = *(const float2*)(x + ((size_t)(b0 + b) * NSITES + (n + 1)) * FEATD + f);
        }

        // B fragments: B[k=f][n=b] = x[b][f]; lane reads x[b16][kc*32 + q*8 .. +7]
        short8 bfr0 = *(const short8*)&x_lds[b16][q * 8];
        short8 bfr1 = *(const short8*)&x_lds[b16][32 + q * 8];

        // A fragments: A[m=c][k=f] = core_t[n][c][f]; 16B contiguous per lane
        short8 af[CTW][2];
        if (USE_T) {
            const ushort* base = core_t + (size_t)n * (1024 * FEATD);
#pragma unroll
            for (int i = 0; i < CTW; ++i) {
                const ushort* p = base + (size_t)((wave * CTW + i) * 16 + b16) * FEATD + q * 8;
                af[i][0] = *(const short8*)p;
                af[i][1] = *(const short8*)(p + 32);
            }
        } else {
            // fallback: gather from original fp32 cores (ws too small)
#pragma unroll
            for (int i = 0; i < CTW; ++i) {
                int c = (wave * CTW + i) * 16 + b16;
                int d = c >> 5, r = c & 31;
                const float* src = cores + (size_t)n * (BOND * FEATD * BOND)
                                 + (size_t)d * (FEATD * BOND) + r;
#pragma unroll
                for (int j = 0; j < 8; ++j) {
                    af[i][0][j] = (short)f2bf(src[(size_t)(q * 8 + j) * BOND]);
                    af[i][1][j] = (short)f2bf(src[(size_t)(32 + q * 8 + j) * BOND]);
                }
            }
        }

        // m^T[c, b] = sum_f core_t[c,f] * x[b,f]
        float4v acc[CTW];
#pragma unroll
        for (int i = 0; i < CTW; ++i) {
            float4v z = {0.f, 0.f, 0.f, 0.f};
            z = __builtin_amdgcn_mfma_f32_16x16x32_bf16(af[i][0], bfr0, z, 0, 0, 0);
            acc[i] = __builtin_amdgcn_mfma_f32_16x16x32_bf16(af[i][1], bfr1, z, 0, 0, 0);
        }

        // stage 2: lane holds m^T[c][b16], c = (wave*8+i)*16 + 4q + g
        //   d = 4*wave + (i>>1), r = 16*(i&1) + 4q + g
        float resd[4];
#pragma unroll
        for (int u = 0; u < 4; ++u) resd[u] = res_lds[b16][wave * 4 + u];
        float ps[2][4] = {{0.f, 0.f, 0.f, 0.f}, {0.f, 0.f, 0.f, 0.f}};
#pragma unroll
        for (int i = 0; i < CTW; ++i) {
            int u = i >> 1, p = i & 1;
#pragma unroll
            for (int g = 0; g < 4; ++g) ps[p][g] += resd[u] * acc[i][g];
        }
#pragma unroll
        for (int p = 0; p < 2; ++p)
#pragma unroll
            for (int g = 0; g < 4; ++g)
                part[wave][16 * p + 4 * q + g][b16] = ps[p][g];
        __syncthreads();

        // cross-wave reduce -> new res; stage x for next site
        {
            int b = t & 15, r = t >> 4;   // 512 threads = 16*32 exactly
            float s = 0.f;
#pragma unroll
            for (int w2 = 0; w2 < NWAVES; ++w2) s += part[w2][r][b];
            res_lds[b][r] = s;            // safe: all res reads were pre-barrier
        }
        if (n + 1 < NSITES) {
            int e = t * 2, b = e >> 6, f = e & 63;
            x_lds[b][f]     = f2bf(xnext.x);
            x_lds[b][f + 1] = f2bf(xnext.y);
        }
        __syncthreads();
    }

    // epilogue: val[b] = res[b]·end;  out[b][j] = val[b]*fc_w[j] + fc_b[j]
    if (t < BTILE) {
        float s = 0.f;
        for (int r = 0; r < BOND; ++r) s += res_lds[t][r] * endv[r];
        val_lds[t] = s;
    }
    __syncthreads();
    {
        int b = t >> 5;       // 16 batches
        int jv = t & 31;      // 32 col-groups
        float v = val_lds[b];
#pragma unroll
        for (int i = 0; i < 2; ++i) {
            int j = jv * 4 + i * 128;
            float4 w4 = *(const float4*)(fc_w + j);
            float4 bb = *(const float4*)(fc_b + j);
            float4 o;
            o.x = v * w4.x + bb.x;
            o.y = v * w4.y + bb.y;
            o.z = v * w4.z + bb.z;
            o.w = v * w4.w + bb.w;
            *(float4*)(out + (size_t)(b0 + b) * OUTD + j) = o;
        }
    }
}

extern "C" void kernel_launch(void* const* d_in, const int* in_sizes, int n_in,
                              void* d_out, int out_size, void* d_ws, size_t ws_size,
                              hipStream_t stream) {
    const float* x      = (const float*)d_in[0];
    const float* cores  = (const float*)d_in[1];
    const float* startv = (const float*)d_in[2];
    const float* endv   = (const float*)d_in[3];
    const float* fc_w   = (const float*)d_in[4];
    const float* fc_b   = (const float*)d_in[5];
    float* out = (float*)d_out;

    const size_t core_t_bytes = (size_t)NSITES * 1024 * FEATD * sizeof(ushort); // 16.8 MB
    if (ws_size >= core_t_bytes) {
        ushort* core_t = (ushort*)d_ws;
        prep_cores<<<NSITES * BOND, 256, 0, stream>>>(cores, core_t);
        mps_chain<true><<<2048 / BTILE, 512, 0, stream>>>(
            x, cores, core_t, startv, endv, fc_w, fc_b, out);
    } else {
        mps_chain<false><<<2048 / BTILE, 512, 0, stream>>>(
            x, cores, nullptr, startv, endv, fc_w, fc_b, out);
    }
}

// Round 2
// 243.509 us; speedup vs baseline: 2.7488x; 2.7488x over previous
//
#include <hip/hip_runtime.h>

// MPS encoder, segmented-chain formulation.
// Per 16-batch tile and 16-site segment: build M_n (fp8 MFMA), fold into
// running 32x32 product P via P^T = M^T P^T (fp8 MFMA, all-wide LDS).
// Combine kernel folds 8 segment matrices into res + epilogue.
// Scaling: core8 = fp8(16*core); P stored = 16*true product; combine /16 per seg.

#define NSITES 128
#define FEATD  64
#define BOND   32
#define OUTD   256
#define BT     16
#define SEGLEN 16
#define NSEG   (NSITES / SEGLEN)   // 8
#define NBT    (2048 / BT)         // 128

#define RSTRIDE 48        // LDS row stride (32 bytes + 16 pad)
#define BSTRIDE 1552      // 32*48 + 16, 16B-aligned batch stride

typedef __attribute__((ext_vector_type(4))) float float4v;

__device__ __forceinline__ unsigned pk4_fp8(float a, float b, float c, float d) {
    int v = __builtin_amdgcn_cvt_pk_fp8_f32(a, b, 0, false);
    v = __builtin_amdgcn_cvt_pk_fp8_f32(c, d, v, true);
    return (unsigned)v;
}

// cores [n][d][f][r] fp32 -> core8 [n][c=d*32+r][f] fp8 (x16), LDS transpose.
__global__ __launch_bounds__(256)
void prep_cores8(const float* __restrict__ cores, unsigned char* __restrict__ core8) {
    __shared__ float tile[FEATD][BOND + 4];
    const int nd = blockIdx.x;            // n*32 + d
    const int t  = threadIdx.x;
    const float* src = cores + (size_t)nd * (FEATD * BOND);
    {   // coalesced read of the 64x32 fp32 tile (flat = f*32 + r)
        int base = t * 8;
        int f = base >> 5, r0 = base & 31;
        float4 v0 = *(const float4*)(src + base);
        float4 v1 = *(const float4*)(src + base + 4);
        tile[f][r0 + 0] = v0.x; tile[f][r0 + 1] = v0.y;
        tile[f][r0 + 2] = v0.z; tile[f][r0 + 3] = v0.w;
        tile[f][r0 + 4] = v1.x; tile[f][r0 + 5] = v1.y;
        tile[f][r0 + 6] = v1.z; tile[f][r0 + 7] = v1.w;
    }
    __syncthreads();
    const int r = t >> 3, f0 = (t & 7) * 8;
    const float s = 16.0f;
    unsigned lo = pk4_fp8(tile[f0 + 0][r] * s, tile[f0 + 1][r] * s,
                          tile[f0 + 2][r] * s, tile[f0 + 3][r] * s);
    unsigned hi = pk4_fp8(tile[f0 + 4][r] * s, tile[f0 + 5][r] * s,
                          tile[f0 + 6][r] * s, tile[f0 + 7][r] * s);
    uint2 w; w.x = lo; w.y = hi;
    *(uint2*)(core8 + ((size_t)nd * BOND + r) * FEATD + f0) = w;
}

__global__ __launch_bounds__(512, 4)
void mps_seg(const float* __restrict__ x, const unsigned char* __restrict__ core8,
             unsigned char* __restrict__ Pout) {
    // MS[b][r][d]: M^T row-major (A-operand of product); build writes 4-d packs.
    // PS[b][d][e]: running product, row-major (B-operand); product writes 4-e packs.
    __shared__ __align__(16) unsigned char MS[BT * BSTRIDE];
    __shared__ __align__(16) unsigned char PS[BT * BSTRIDE];
    __shared__ __align__(16) unsigned char XS[BT * 72];

    const int t    = threadIdx.x;
    const int wave = t >> 6;
    const int lane = t & 63;
    const int cl   = lane & 15;
    const int q    = lane >> 4;
    const int bt   = blockIdx.x;          // batch tile
    const int seg  = blockIdx.y;
    const int b0   = bt * BT;

    // init PS = 16*I  (fp8 16.0 = 0x58)
    {
        int b = t >> 5, d = t & 31;
        unsigned w[8];
#pragma unroll
        for (int dw = 0; dw < 8; ++dw)
            w[dw] = ((d >> 2) == dw) ? (0x58u << ((d & 3) * 8)) : 0u;
        uint4* p = (uint4*)&PS[b * BSTRIDE + d * RSTRIDE];
        p[0] = make_uint4(w[0], w[1], w[2], w[3]);
        p[1] = make_uint4(w[4], w[5], w[6], w[7]);
    }

    // x prefetch for first site
    const int xb = t >> 5, xf = (t & 31) * 2;   // 16 batches x 32 pairs
    float2 xf2 = *(const float2*)(x + ((size_t)(b0 + xb) * NSITES + seg * SEGLEN) * FEATD + xf);

    for (int k = 0; k < SEGLEN; ++k) {
        const int n = seg * SEGLEN + k;

        // A-fragment global loads for build (issued early; core8 is L2-hot)
        long af[16];
        {
            const unsigned char* base = core8 + (size_t)n * (1024 * FEATD);
#pragma unroll
            for (int i = 0; i < 8; ++i) {
                const unsigned char* p =
                    base + (size_t)((wave * 8 + i) * 16 + cl) * FEATD + q * 8;
                af[i * 2 + 0] = *(const long*)p;
                af[i * 2 + 1] = *(const long*)(p + 32);
            }
        }

        // stage x (fp8) into LDS
        {
            int v = __builtin_amdgcn_cvt_pk_fp8_f32(xf2.x, xf2.y, 0, false);
            *(unsigned short*)&XS[xb * 72 + xf] = (unsigned short)(v & 0xffff);
        }
        __syncthreads();   // barrier 1: XS visible; prev product's MS reads done

        // build: m^T[c, b] with c = (wave*8+i)*16 + 4q+g, b = cl
        long bx0 = *(const long*)&XS[cl * 72 + q * 8];
        long bx1 = *(const long*)&XS[cl * 72 + 32 + q * 8];
        float4v acc[8];
#pragma unroll
        for (int i = 0; i < 8; ++i) {
            float4v z = {0.f, 0.f, 0.f, 0.f};
            z = __builtin_amdgcn_mfma_f32_16x16x32_fp8_fp8(af[i * 2 + 0], bx0, z, 0, 0, 0);
            acc[i] = __builtin_amdgcn_mfma_f32_16x16x32_fp8_fp8(af[i * 2 + 1], bx1, z, 0, 0, 0);
        }

        // MS[b=cl][r=16p+4q+g][d = wave*4 + u], pack u=0..3 -> one b32
#pragma unroll
        for (int p = 0; p < 2; ++p)
#pragma unroll
            for (int g = 0; g < 4; ++g) {
                unsigned w = pk4_fp8(acc[0 + p][g], acc[2 + p][g],
                                     acc[4 + p][g], acc[6 + p][g]);
                *(unsigned*)&MS[cl * BSTRIDE + (16 * p + 4 * q + g) * RSTRIDE + wave * 4] = w;
            }

        // x prefetch next site
        if (k + 1 < SEGLEN)
            xf2 = *(const float2*)(x + ((size_t)(b0 + xb) * NSITES + n + 1) * FEATD + xf);

        __syncthreads();   // barrier 2: MS visible

        // product: Q^T_new = M^T * Q^T ; wave owns batches 2w, 2w+1
        long pa[2][2], pb[2][2];
#pragma unroll
        for (int bi = 0; bi < 2; ++bi) {
            int bb = wave * 2 + bi;
#pragma unroll
            for (int h = 0; h < 2; ++h) {
                pa[bi][h] = *(const long*)&MS[bb * BSTRIDE + (h * 16 + cl) * RSTRIDE + q * 8];
                pb[bi][h] = *(const long*)&PS[bb * BSTRIDE + (h * 16 + cl) * RSTRIDE + q * 8];
            }
        }
        float4v pacc[2][2][2];
#pragma unroll
        for (int bi = 0; bi < 2; ++bi)
#pragma unroll
            for (int I = 0; I < 2; ++I)
#pragma unroll
                for (int J = 0; J < 2; ++J) {
                    float4v z = {0.f, 0.f, 0.f, 0.f};
                    pacc[bi][I][J] =
                        __builtin_amdgcn_mfma_f32_16x16x32_fp8_fp8(pa[bi][I], pb[bi][J], z, 0, 0, 0);
                }
        // write back PS[b][d = J*16+cl][e = I*16+4q .. +3], scaled 1/16
#pragma unroll
        for (int bi = 0; bi < 2; ++bi) {
            int bb = wave * 2 + bi;
#pragma unroll
            for (int I = 0; I < 2; ++I)
#pragma unroll
                for (int J = 0; J < 2; ++J) {
                    float4v c = pacc[bi][I][J];
                    unsigned w = pk4_fp8(c[0] * 0.0625f, c[1] * 0.0625f,
                                         c[2] * 0.0625f, c[3] * 0.0625f);
                    *(unsigned*)&PS[bb * BSTRIDE + (J * 16 + cl) * RSTRIDE + I * 16 + q * 4] = w;
                }
        }
    }

    __syncthreads();
    // dump PS -> Pout[seg][b][d][e]
    {
        int b = t >> 5, d = t & 31;
        const uint4* p = (const uint4*)&PS[b * BSTRIDE + d * RSTRIDE];
        uint4* g = (uint4*)(Pout + (((size_t)seg * 2048 + b0 + b) * 1024 + d * 32));
        g[0] = p[0];
        g[1] = p[1];
    }
}

__global__ __launch_bounds__(256)
void combine(const unsigned char* __restrict__ Pout, const float* __restrict__ startv,
             const float* __restrict__ endv, const float* __restrict__ fc_w,
             const float* __restrict__ fc_b, float* __restrict__ out) {
    __shared__ __align__(16) unsigned char st[8 * 1024];
    __shared__ float resA[8][33], resB[8][33];
    __shared__ float val[8];
    const int t  = threadIdx.x;
    const int b0 = blockIdx.x * 8;
    const int bb = t >> 5, r = t & 31;

    resA[bb][r] = startv[r];
    for (int s = 0; s < NSEG; ++s) {
        {   // stage 8 KB (8 batches x 1 KB), coalesced
            const uint4* g = (const uint4*)(Pout + ((size_t)s * 2048 + b0) * 1024 + (size_t)t * 32);
            uint4* p = (uint4*)&st[t * 32];
            p[0] = g[0];
            p[1] = g[1];
        }
        __syncthreads();
        const float* rin = (s & 1) ? &resB[bb][0] : &resA[bb][0];
        float* rout      = (s & 1) ? &resA[bb][0] : &resB[bb][0];
        float acc = 0.f;
#pragma unroll
        for (int d = 0; d < BOND; ++d) {
            int byte = st[bb * 1024 + d * 32 + r];
            acc += rin[d] * __builtin_amdgcn_cvt_f32_fp8(byte, 0);
        }
        rout[r] = acc * 0.0625f;
        __syncthreads();
    }
    // NSEG even -> result in resA
    float prod = resA[bb][r] * endv[r];
#pragma unroll
    for (int off = 16; off >= 1; off >>= 1) prod += __shfl_down(prod, off, 32);
    if (r == 0) val[bb] = prod;
    __syncthreads();

    const float v = val[t >> 5];
    const int j0 = (t & 31) * 8;
    const int ob = b0 + (t >> 5);
#pragma unroll
    for (int i = 0; i < 2; ++i) {
        int j = j0 + i * 4;
        float4 w4 = *(const float4*)(fc_w + j);
        float4 bbv = *(const float4*)(fc_b + j);
        float4 o;
        o.x = v * w4.x + bbv.x;
        o.y = v * w4.y + bbv.y;
        o.z = v * w4.z + bbv.z;
        o.w = v * w4.w + bbv.w;
        *(float4*)(out + (size_t)ob * OUTD + j) = o;
    }
}

extern "C" void kernel_launch(void* const* d_in, const int* in_sizes, int n_in,
                              void* d_out, int out_size, void* d_ws, size_t ws_size,
                              hipStream_t stream) {
    const float* x      = (const float*)d_in[0];
    const float* cores  = (const float*)d_in[1];
    const float* startv = (const float*)d_in[2];
    const float* endv   = (const float*)d_in[3];
    const float* fc_w   = (const float*)d_in[4];
    const float* fc_b   = (const float*)d_in[5];
    float* out = (float*)d_out;

    unsigned char* core8 = (unsigned char*)d_ws;                       // 8.4 MB
    unsigned char* Pout  = core8 + (size_t)NSITES * 1024 * FEATD;      // 16.8 MB

    prep_cores8<<<NSITES * BOND, 256, 0, stream>>>(cores, core8);
    mps_seg<<<dim3(NBT, NSEG), 512, 0, stream>>>(x, core8, Pout);
    combine<<<2048 / 8, 256, 0, stream>>>(Pout, startv, endv, fc_w, fc_b, out);
}